// Round 4
// baseline (191.827 us; speedup 1.0000x reference)
//
#include <hip/hip_runtime.h>

typedef __bf16 bf16;
typedef __bf16 bf16x8 __attribute__((ext_vector_type(8)));
typedef float f32x4 __attribute__((ext_vector_type(4)));

#define EPS 1e-8f

constexpr int B = 16, CI = 256, CO = 256, S = 512, H = 64, W = 64;
constexpr int PH = 66;                    // padded spatial dim
constexpr int TAPS = 9;                   // 3x3

// 16-byte "chunks" (8 bf16):
//   wd   chunks: [tap][ci8=32][co=256]    -> UNMODULATED shared weights, 1.18 MB
//   xpad chunks: [b][row=66][ci8=32][col=66] -> style-scaled input, 35.7 MB
constexpr size_t WS_WD    = 0;                            // 1,179,648 B
constexpr size_t WS_XPAD  = 1179648;
constexpr size_t WS_STYLE = WS_XPAD + (size_t)B*PH*32*PH*16;  // [B][CI] f32
constexpr size_t WS_WSQT  = WS_STYLE + 16384;             // [ci][co] f32 = 256 KB
constexpr size_t WS_INV   = WS_WSQT + 262144;             // [B][CO] f32

// ---------------------------------------------------------------- prep1 ----
// blocks 0..255:    wprep  — wts [CO][CI][3][3] f32 -> wd chunks + wsqT
// blocks 256..1279: style  — style[b][c] = y[b]·sw[c] + sb[c]
__global__ void prep1_kernel(const float* __restrict__ y,
                             const float* __restrict__ sw,
                             const float* __restrict__ sb,
                             const float* __restrict__ wts,
                             bf16x8* __restrict__ wd,
                             float* __restrict__ wsqT,
                             float* __restrict__ style) {
    __shared__ float t[8 * 289];   // stride 289: bank-conflict-free gathers
    int i = blockIdx.x;
    if (i < 256) {                 // ---- wprep: 8co x 32ci tile ----
        int cb = i & 31;           // co block 0..31 (8 co each)
        int ib = i >> 5;           // ci block 0..7  (32 ci each)
        const float* src = wts + ((size_t)cb * 8) * (CI * TAPS) + ib * 32 * TAPS;
        for (int e = threadIdx.x; e < 8 * 288; e += 256) {
            int col = e / 288, idx = e - col * 288;        // col = co_l
            t[col * 289 + idx] = src[(size_t)col * (CI * TAPS) + idx];
        }
        __syncthreads();
        // wd chunks: tap(9) x ci8_l(4) x co_l(8) = 288 (strided: 288 > 256)
        for (int c = threadIdx.x; c < 288; c += 256) {
            int co_l = c & 7, ci8_l = (c >> 3) & 3, tap = c >> 5;
            bf16x8 v;
#pragma unroll
            for (int j = 0; j < 8; ++j) v[j] = (bf16)t[co_l * 289 + (ci8_l * 8 + j) * 9 + tap];
            wd[((size_t)tap * 32 + ib * 4 + ci8_l) * CO + cb * 8 + co_l] = v;
        }
        // wsqT: ci_l(32) x co_l(8) = 256
        int c = threadIdx.x;
        int co_l = c & 7, ci_l = c >> 3;
        float s = 0.f;
#pragma unroll
        for (int tap = 0; tap < 9; ++tap) {
            float w = t[co_l * 289 + ci_l * 9 + tap];
            s += w * w;
        }
        wsqT[((size_t)(ib * 32 + ci_l)) * CO + cb * 8 + co_l] = s;
    } else {                       // ---- style: one wave per (b,c) ----
        int i2 = i - 256;
        int b = i2 >> 6;
        int c = (i2 & 63) * 4 + (threadIdx.x >> 6);
        int lane = threadIdx.x & 63;
        const float* yr = y + (size_t)b * S;
        const float* wr = sw + (size_t)c * S;
        float acc = 0.f;
#pragma unroll
        for (int k = 0; k < 8; ++k) acc += yr[lane + k * 64] * wr[lane + k * 64];
        for (int off = 32; off; off >>= 1) acc += __shfl_down(acc, off, 64);
        if (lane == 0) style[b * CI + c] = acc + sb[c];
    }
}

// ---------------------------------------------------------------- prep2 ----
// ROUND 9 REWRITE (old version: LDS-transpose staging, 4 blocks/CU, serial
// 256-iter invstd latency chain; preps measured ~115us vs ~22us BW floor).
// New structure, no LDS transpose, no barriers in the hot path:
//   blocks 0..8191:    xpad main — wave = (b, ci8, row), lane = col.
//     8 coalesced 256B wave-loads (one per ci in the chunk) + scale + cvt
//     + one contiguous 1KB/wave chunk store.  8 blocks/CU occupancy.
//   blocks 8192..8447: border zeroing (8320 chunks/b spread over 16 blocks/b)
//   blocks 8448..8463: invstd — 8-way unrolled (8 loads in flight), style^2
//     staged in LDS.
__global__ void prep2_kernel(const float* __restrict__ x,
                             const float* __restrict__ style,
                             const float* __restrict__ wsqT,
                             bf16x8* __restrict__ xp,
                             float* __restrict__ invstd) {
    __shared__ float st2[256];
    int i = blockIdx.x;
    if (i < 8192) {                // ---- xpad main ----
        int b = i >> 9, rem = i & 511;
        int ci8 = rem & 31;
        int row = ((rem >> 5) << 2) + (threadIdx.x >> 6);
        int col = threadIdx.x & 63;
        const float* xb = x + (((size_t)b * CI + ci8 * 8) * H + row) * W + col;
        const float* st = style + b * CI + ci8 * 8;
        bf16x8 v;
#pragma unroll
        for (int j = 0; j < 8; ++j) v[j] = (bf16)(xb[(size_t)j * H * W] * st[j]);
        xp[(((size_t)b * PH + row + 1) * 32 + ci8) * PH + col + 1] = v;
        return;
    }
    if (i < 8448) {                // ---- borders: rows {0,65} full + cols {0,65} ----
        int bi = i - 8192;
        int b = bi >> 4, part = bi & 15;       // 16 parts x 520 = 8320 chunks
        bf16x8 z;
#pragma unroll
        for (int j = 0; j < 8; ++j) z[j] = (bf16)0.f;
        for (int t = threadIdx.x; t < 520; t += 256) {
            int idx = part * 520 + t;
            int row, ci8, col;
            if (idx < 4224) {                  // rows 0 and 65, all 66 cols
                int rowsel = idx / 2112;
                int rem = idx - rowsel * 2112;
                row = rowsel ? (PH - 1) : 0;
                ci8 = rem / 66;
                col = rem - ci8 * 66;
            } else {                           // cols 0 and 65, rows 1..64
                int j2 = idx - 4224;
                int colsel = j2 >> 11;
                int rem = j2 & 2047;
                row = 1 + (rem >> 5);
                ci8 = rem & 31;
                col = colsel ? (PH - 1) : 0;
            }
            xp[(((size_t)b * PH + row) * 32 + ci8) * PH + col] = z;
        }
        return;
    }
    // ---- invstd ----
    int b = i - 8448, co = threadIdx.x;
    float s = style[b * CI + co];
    st2[co] = s * s;
    __syncthreads();
    float a0 = 0.f, a1 = 0.f, a2 = 0.f, a3 = 0.f;
    float a4 = 0.f, a5 = 0.f, a6 = 0.f, a7 = 0.f;
    for (int ci = 0; ci < CI; ci += 8) {       // 8 independent load streams
        a0 += wsqT[(size_t)(ci + 0) * CO + co] * st2[ci + 0];
        a1 += wsqT[(size_t)(ci + 1) * CO + co] * st2[ci + 1];
        a2 += wsqT[(size_t)(ci + 2) * CO + co] * st2[ci + 2];
        a3 += wsqT[(size_t)(ci + 3) * CO + co] * st2[ci + 3];
        a4 += wsqT[(size_t)(ci + 4) * CO + co] * st2[ci + 4];
        a5 += wsqT[(size_t)(ci + 5) * CO + co] * st2[ci + 5];
        a6 += wsqT[(size_t)(ci + 6) * CO + co] * st2[ci + 6];
        a7 += wsqT[(size_t)(ci + 7) * CO + co] * st2[ci + 7];
    }
    float acc = ((a0 + a1) + (a2 + a3)) + ((a4 + a5) + (a6 + a7));
    invstd[b * CO + co] = rsqrtf(acc + EPS);
}

// ----------------------------------------------------------------- conv ----
// Implicit GEMM with SHARED unmodulated weights; demod in epilogue.
// Block 256 thr = 4 waves; block tile 128co x (4 rows x 64 cols);
// wave tile 64co x (2 rows x 64 cols) = 4x8 mfma_f32_16x16x32_bf16.
// Grid 1D 512 = exactly 2 blocks/CU, whole grid co-resident at (256,2).
//
// ROUND 6: 1-deep register double-buffer of per-tap operands + sched_barrier.
// ROUND 7 FAILED: (256,4) halved the VGPR budget -> spill (WRITE_SIZE 376MB).
// ROUND 8: 64co x 128sp wave tile; VGPR=128 + acc in 128 AGPRs = full
//   256/wave budget at 2 waves/SIMD.  75.6us, MfmaUtil 42%.  Register file
//   is now the binding constraint; deeper prefetch impossible at 2 waves.
// ROUND 9 change: T5 s_setprio(1) around the MFMA cluster.  Conv has no
//   barriers; the 2 waves/SIMD free-run at different loop phases (role
//   diversity = the attn/m191 regime, not the lockstep/m190 regime), so
//   prio lets the scheduler favor the MFMA-entering wave.
#define LOAD_TAP(c8_, kh_, kw_, av_, bv_)                                         \
    {                                                                             \
        const bf16x8* wq_ = wbase + ((size_t)((kh_)*3 + (kw_)) * 32 + (c8_)) * CO;\
        const bf16x8* xq_ = xbase + ((size_t)(kh_) * 32 * PH + (size_t)(c8_) * PH + (kw_)); \
        _Pragma("unroll") for (int a_ = 0; a_ < 4; ++a_) (av_)[a_] = wq_[a_ * 16];\
        _Pragma("unroll") for (int jr_ = 0; jr_ < 2; ++jr_)                       \
            _Pragma("unroll") for (int jc_ = 0; jc_ < 4; ++jc_)                   \
                (bv_)[jr_ * 4 + jc_] = xq_[(size_t)jr_ * 32 * PH + jc_ * 16];     \
    }

#define MFMA_STEP(av_, bv_)                                                       \
    __builtin_amdgcn_s_setprio(1);                                                \
    _Pragma("unroll") for (int a_ = 0; a_ < 4; ++a_)                              \
        _Pragma("unroll") for (int j_ = 0; j_ < 8; ++j_)                          \
            acc[a_][j_] = __builtin_amdgcn_mfma_f32_16x16x32_bf16(                \
                (av_)[a_], (bv_)[j_], acc[a_][j_], 0, 0, 0);                      \
    __builtin_amdgcn_s_setprio(0);

__global__ __launch_bounds__(256, 2) void conv_kernel(
                            const bf16x8* __restrict__ wd,
                            const bf16x8* __restrict__ xp,
                            const float* __restrict__ bias,
                            const float* __restrict__ invstd,
                            float* __restrict__ out) {
    int i = blockIdx.x;
    int xcd = i & 7, t = i >> 3;               // t: 0..63
    int b = xcd * 2 + (t >> 5);                // 2 samples per XCD
    int rest = t & 31;
    int cotile = rest & 1, rowquad = rest >> 1; // 16 row-quads of 4 rows
    int tid = threadIdx.x;
    int wave = tid >> 6, lane = tid & 63;
    int co_half = wave & 1, sp_half = wave >> 1;
    int r0 = rowquad * 4 + sp_half * 2;        // wave's first output row (+jr)
    int co_base = cotile * 128 + co_half * 64;
    int lm = lane & 15, lk = lane >> 4;

    f32x4 acc[4][8] = {};

    const bf16x8* xpb = xp + (size_t)b * PH * 32 * PH;
    // lane-resolved base pointers; per-step offsets are wave-uniform consts
    const bf16x8* wbase = wd + (size_t)lk * CO + co_base + lm;        // +(tap*32+c8)*CO
    const bf16x8* xbase = xpb + ((size_t)r0 * 32 + lk) * PH + lm;     // +(kh*32+c8)*PH+kw (+jr*32*PH)

    bf16x8 av0[4], bv0[8], av1[4], bv1[8];

    LOAD_TAP(0, 0, 0, av0, bv0);               // prologue: step 0 operands

#pragma unroll 1
    for (int c8a = 0; c8a < 32; c8a += 8) {    // 4 super-iters of 18 steps
#pragma unroll
        for (int v = 0; v < 18; ++v) {
            // current step: half = v/9 (ci8 sub-block), tap = v%9 — all
            // compile-time after unroll.  next-step indices:
            const int ntap = (v + 1) % 9;
            const int nkh = ntap / 3, nkw = ntap % 3;
            int nc8 = (v == 17) ? ((c8a + 8) & 31)          // next super-iter
                                : (c8a + ((v + 1) / 9) * 4); // (wrap load at the
                                                             // very end is dead
                                                             // but in-bounds)
            if ((v & 1) == 0) {
                LOAD_TAP(nc8, nkh, nkw, av1, bv1);
                __builtin_amdgcn_sched_barrier(0);   // loads stay above MFMAs
                MFMA_STEP(av0, bv0);
            } else {
                LOAD_TAP(nc8, nkh, nkw, av0, bv0);
                __builtin_amdgcn_sched_barrier(0);
                MFMA_STEP(av1, bv1);
            }
        }
    }

    // epilogue: D col = lm (spatial, + jc*16), row = lk*4 + g (co, + a*16)
#pragma unroll
    for (int a = 0; a < 4; ++a) {
#pragma unroll
        for (int g = 0; g < 4; ++g) {
            int co = co_base + a * 16 + lk * 4 + g;
            float sc = invstd[b * CO + co];
            float bvl = bias[co];
#pragma unroll
            for (int jr = 0; jr < 2; ++jr) {
                size_t o = (((size_t)b * CO + co) * H + r0 + jr) * W;
#pragma unroll
                for (int jc = 0; jc < 4; ++jc)
                    out[o + jc * 16 + lm] = acc[a][jr * 4 + jc][g] * sc + bvl;
            }
        }
    }
}

// --------------------------------------------------------------- launch ----
extern "C" void kernel_launch(void* const* d_in, const int* in_sizes, int n_in,
                              void* d_out, int out_size, void* d_ws, size_t ws_size,
                              hipStream_t stream) {
    const float* x    = (const float*)d_in[0];
    const float* y    = (const float*)d_in[1];
    const float* wts  = (const float*)d_in[2];
    const float* bias = (const float*)d_in[3];
    const float* sw   = (const float*)d_in[4];
    const float* sb   = (const float*)d_in[5];
    float* out = (float*)d_out;

    char* ws = (char*)d_ws;
    bf16x8* wd    = (bf16x8*)(ws + WS_WD);
    bf16x8* xpad  = (bf16x8*)(ws + WS_XPAD);
    float* style  = (float*)(ws + WS_STYLE);
    float* wsqT   = (float*)(ws + WS_WSQT);
    float* invstd = (float*)(ws + WS_INV);

    prep1_kernel<<<dim3(1280), dim3(256), 0, stream>>>(y, sw, sb, wts, wd, wsqT, style);
    prep2_kernel<<<dim3(8464), dim3(256), 0, stream>>>(x, style, wsqT, xpad, invstd);
    conv_kernel<<<dim3(512), dim3(256), 0, stream>>>(wd, xpad, bias, invstd, out);
}